// Round 1
// baseline (5164.199 us; speedup 1.0000x reference)
//
#include <hip/hip_runtime.h>
#include <utility>

constexpr int NUM_USERS = 100000;
constexpr int NUM_ITEMS = 50000;
constexpr int DIM = 64;
constexpr int NNZ_R = 3200000;
constexpr int NNZ_S = 2000000;

// One edge per 64-lane wave: lane d handles dim d.
// out[rows[k]][d] += vals[k] * x[cols[k]][d]
__global__ void spmm_atomic(const int* __restrict__ rows, const int* __restrict__ cols,
                            const float* __restrict__ vals, const float* __restrict__ x,
                            float* __restrict__ out, int nnz) {
    int edge = blockIdx.x * 4 + (threadIdx.x >> 6);   // 4 waves per 256-thread block
    if (edge >= nnz) return;
    int d = threadIdx.x & 63;
    int r = rows[edge];
    int c = cols[edge];
    float v = vals[edge];
    atomicAdd(out + (size_t)r * DIM + d, v * x[(size_t)c * DIM + d]);
}

// acc += x  (float4-vectorized, grid-stride)
__global__ void acc_add(float* __restrict__ acc, const float* __restrict__ x, int n4) {
    int i = blockIdx.x * blockDim.x + threadIdx.x;
    int stride = gridDim.x * blockDim.x;
    for (; i < n4; i += stride) {
        float4 a = reinterpret_cast<float4*>(acc)[i];
        float4 b = reinterpret_cast<const float4*>(x)[i];
        a.x += b.x; a.y += b.y; a.z += b.z; a.w += b.w;
        reinterpret_cast<float4*>(acc)[i] = a;
    }
}

// out[row] = l2norm(0.6*uacc[row]/4 + 0.4*sacc[row]/3), one row per wave
__global__ void finalize_user(const float* __restrict__ uacc, const float* __restrict__ sacc,
                              float* __restrict__ out) {
    int row = blockIdx.x * 4 + (threadIdx.x >> 6);
    if (row >= NUM_USERS) return;
    int d = threadIdx.x & 63;
    size_t idx = (size_t)row * DIM + d;
    float val = 0.15f * uacc[idx] + (0.4f / 3.0f) * sacc[idx];
    float sq = val * val;
    #pragma unroll
    for (int off = 32; off; off >>= 1) sq += __shfl_xor(sq, off, 64);
    out[idx] = val / fmaxf(sqrtf(sq), 1e-12f);
}

// out[row] = l2norm(iacc[row]/4), one row per wave
__global__ void finalize_item(const float* __restrict__ iacc, float* __restrict__ out) {
    int row = blockIdx.x * 4 + (threadIdx.x >> 6);
    if (row >= NUM_ITEMS) return;
    int d = threadIdx.x & 63;
    size_t idx = (size_t)row * DIM + d;
    float val = 0.25f * iacc[idx];
    float sq = val * val;
    #pragma unroll
    for (int off = 32; off; off >>= 1) sq += __shfl_xor(sq, off, 64);
    out[idx] = val / fmaxf(sqrtf(sq), 1e-12f);
}

extern "C" void kernel_launch(void* const* d_in, const int* in_sizes, int n_in,
                              void* d_out, int out_size, void* d_ws, size_t ws_size,
                              hipStream_t stream) {
    const float* user_emb = (const float*)d_in[0];
    const float* item_emb = (const float*)d_in[1];
    const float* r_vals   = (const float*)d_in[2];
    const float* s_vals   = (const float*)d_in[3];
    const int*   r_rows   = (const int*)d_in[4];
    const int*   r_cols   = (const int*)d_in[5];
    const int*   s_rows   = (const int*)d_in[6];
    const int*   s_cols   = (const int*)d_in[7];

    const size_t U = (size_t)NUM_USERS * DIM;   // 6.4M floats
    const size_t I = (size_t)NUM_ITEMS * DIM;   // 3.2M floats

    float* ws    = (float*)d_ws;
    float* u_cur  = ws;            // [U]
    float* u_next = u_cur + U;     // [U]
    float* u_acc  = u_next + U;    // [U]
    float* s_acc  = u_acc + U;     // [U]
    float* i_cur  = s_acc + U;     // [I]
    float* i_next = i_cur + I;     // [I]
    float* i_acc  = i_next + I;    // [I]  total = 4U+3I floats = 140.8 MB

    hipMemcpyAsync(u_cur, user_emb, U * sizeof(float), hipMemcpyDeviceToDevice, stream);
    hipMemcpyAsync(u_acc, user_emb, U * sizeof(float), hipMemcpyDeviceToDevice, stream);
    hipMemcpyAsync(i_cur, item_emb, I * sizeof(float), hipMemcpyDeviceToDevice, stream);
    hipMemcpyAsync(i_acc, item_emb, I * sizeof(float), hipMemcpyDeviceToDevice, stream);

    dim3 blk(256);
    int spmmR_blocks = (NNZ_R + 3) / 4;
    int spmmS_blocks = (NNZ_S + 3) / 4;

    // LightGCN bipartite propagation: 3 layers, simultaneous update from old (u,i)
    for (int layer = 0; layer < 3; ++layer) {
        hipMemsetAsync(u_next, 0, U * sizeof(float), stream);
        hipMemsetAsync(i_next, 0, I * sizeof(float), stream);
        spmm_atomic<<<spmmR_blocks, blk, 0, stream>>>(r_rows, r_cols, r_vals, i_cur, u_next, NNZ_R);
        spmm_atomic<<<spmmR_blocks, blk, 0, stream>>>(r_cols, r_rows, r_vals, u_cur, i_next, NNZ_R);
        acc_add<<<2048, blk, 0, stream>>>(u_acc, u_next, (int)(U / 4));
        acc_add<<<2048, blk, 0, stream>>>(i_acc, i_next, (int)(I / 4));
        std::swap(u_cur, u_next);
        std::swap(i_cur, i_next);
    }

    // Social propagation: 2 layers; reuse bipartite u ping-pong buffers
    float* sc = u_cur;
    float* sn = u_next;
    hipMemcpyAsync(sc,    user_emb, U * sizeof(float), hipMemcpyDeviceToDevice, stream);
    hipMemcpyAsync(s_acc, user_emb, U * sizeof(float), hipMemcpyDeviceToDevice, stream);
    for (int layer = 0; layer < 2; ++layer) {
        hipMemsetAsync(sn, 0, U * sizeof(float), stream);
        spmm_atomic<<<spmmS_blocks, blk, 0, stream>>>(s_rows, s_cols, s_vals, sc, sn, NNZ_S);
        acc_add<<<2048, blk, 0, stream>>>(s_acc, sn, (int)(U / 4));
        std::swap(sc, sn);
    }

    finalize_user<<<(NUM_USERS + 3) / 4, blk, 0, stream>>>(u_acc, s_acc, (float*)d_out);
    finalize_item<<<(NUM_ITEMS + 3) / 4, blk, 0, stream>>>(i_acc, (float*)d_out + U);
}

// Round 2
// 2446.714 us; speedup vs baseline: 2.1107x; 2.1107x over previous
//
#include <hip/hip_runtime.h>
#include <utility>

constexpr int NUM_USERS = 100000;
constexpr int NUM_ITEMS = 50000;
constexpr int DIM = 64;
constexpr int NNZ_R = 3200000;
constexpr int NNZ_S = 2000000;

// ---- CSR build: histogram -> exclusive scan -> scatter ----

__global__ void hist_kernel(const int* __restrict__ rows, int* __restrict__ counts, int nnz) {
    int i = blockIdx.x * blockDim.x + threadIdx.x;
    int stride = gridDim.x * blockDim.x;
    for (; i < nnz; i += stride) atomicAdd(&counts[rows[i]], 1);
}

// Single-block exclusive scan over n counts. buf: counts in, cursor out (same values
// as rowptr). rowptr[n] gets the total.
__global__ __launch_bounds__(1024) void exscan_kernel(int* __restrict__ buf,
                                                      int* __restrict__ rowptr, int n) {
    __shared__ int part[1024];
    int t = threadIdx.x;
    int chunk = (n + 1023) >> 10;
    int lo = t * chunk, hi = min(lo + chunk, n);
    int s = 0;
    for (int i = lo; i < hi; ++i) s += buf[i];
    part[t] = s;
    __syncthreads();
    for (int off = 1; off < 1024; off <<= 1) {
        int v = (t >= off) ? part[t - off] : 0;
        __syncthreads();
        part[t] += v;
        __syncthreads();
    }
    int excl = (t == 0) ? 0 : part[t - 1];
    for (int i = lo; i < hi; ++i) {
        int c = buf[i];          // read before overwrite (buf aliases cursor)
        rowptr[i] = excl;
        buf[i] = excl;           // cursor
        excl += c;
    }
    if (t == 0) rowptr[n] = part[1023];
}

__global__ void scatter_kernel(const int* __restrict__ rows, const int* __restrict__ cols,
                               const float* __restrict__ vals, int* __restrict__ cursor,
                               int* __restrict__ out_cols, float* __restrict__ out_vals, int nnz) {
    int i = blockIdx.x * blockDim.x + threadIdx.x;
    int stride = gridDim.x * blockDim.x;
    for (; i < nnz; i += stride) {
        int r = rows[i];
        int pos = atomicAdd(&cursor[r], 1);
        out_cols[pos] = cols[i];
        out_vals[pos] = vals[i];
    }
}

// ---- CSR SpMM: one output row per 64-lane wave, register accumulation,
//      fused weighted accumulate into acc (d_out). ----
__global__ void spmm_csr(const int* __restrict__ rowptr, const int* __restrict__ cols,
                         const float* __restrict__ vals, const float* __restrict__ x,
                         float* __restrict__ out, float* __restrict__ acc, float w, int nrows) {
    int row = blockIdx.x * 4 + (threadIdx.x >> 6);
    if (row >= nrows) return;
    int d = threadIdx.x & 63;
    int e = rowptr[row], end = rowptr[row + 1];
    float s0 = 0.f, s1 = 0.f, s2 = 0.f, s3 = 0.f;
    for (; e + 4 <= end; e += 4) {   // 4 independent gathers in flight
        int c0 = cols[e], c1 = cols[e + 1], c2 = cols[e + 2], c3 = cols[e + 3];
        float v0 = vals[e], v1 = vals[e + 1], v2 = vals[e + 2], v3 = vals[e + 3];
        s0 += v0 * x[c0 * DIM + d];
        s1 += v1 * x[c1 * DIM + d];
        s2 += v2 * x[c2 * DIM + d];
        s3 += v3 * x[c3 * DIM + d];
    }
    for (; e < end; ++e) s0 += vals[e] * x[cols[e] * DIM + d];
    float sum = (s0 + s1) + (s2 + s3);
    int idx = row * DIM + d;
    out[idx] = sum;
    acc[idx] += w * sum;
}

// init: u_cur = user_emb, i_cur = item_emb, acc_u = wu*user_emb, acc_i = wi*item_emb
__global__ void init_kernel(const float* __restrict__ ue, const float* __restrict__ ie,
                            float* __restrict__ u_cur, float* __restrict__ i_cur,
                            float* __restrict__ acc_u, float* __restrict__ acc_i,
                            int u4, int i4) {
    const float wu = 0.6f / 4.0f + 0.4f / 3.0f;
    const float wi = 0.25f;
    int i = blockIdx.x * blockDim.x + threadIdx.x;
    int stride = gridDim.x * blockDim.x;
    int n4 = u4 + i4;
    for (; i < n4; i += stride) {
        if (i < u4) {
            float4 v = reinterpret_cast<const float4*>(ue)[i];
            reinterpret_cast<float4*>(u_cur)[i] = v;
            float4 a = make_float4(wu * v.x, wu * v.y, wu * v.z, wu * v.w);
            reinterpret_cast<float4*>(acc_u)[i] = a;
        } else {
            int j = i - u4;
            float4 v = reinterpret_cast<const float4*>(ie)[j];
            reinterpret_cast<float4*>(i_cur)[j] = v;
            float4 a = make_float4(wi * v.x, wi * v.y, wi * v.z, wi * v.w);
            reinterpret_cast<float4*>(acc_i)[j] = a;
        }
    }
}

// L2-normalize every 64-float row of out in place (weights already folded in acc).
__global__ void finalize_kernel(float* __restrict__ out, int nrows) {
    int row = blockIdx.x * 4 + (threadIdx.x >> 6);
    if (row >= nrows) return;
    int d = threadIdx.x & 63;
    int idx = row * DIM + d;
    float val = out[idx];
    float sq = val * val;
    #pragma unroll
    for (int off = 32; off; off >>= 1) sq += __shfl_xor(sq, off, 64);
    out[idx] = val / fmaxf(sqrtf(sq), 1e-12f);
}

extern "C" void kernel_launch(void* const* d_in, const int* in_sizes, int n_in,
                              void* d_out, int out_size, void* d_ws, size_t ws_size,
                              hipStream_t stream) {
    const float* user_emb = (const float*)d_in[0];
    const float* item_emb = (const float*)d_in[1];
    const float* r_vals   = (const float*)d_in[2];
    const float* s_vals   = (const float*)d_in[3];
    const int*   r_rows   = (const int*)d_in[4];
    const int*   r_cols   = (const int*)d_in[5];
    const int*   s_rows   = (const int*)d_in[6];
    const int*   s_cols   = (const int*)d_in[7];

    const size_t U = (size_t)NUM_USERS * DIM;   // 6.4M floats
    const size_t I = (size_t)NUM_ITEMS * DIM;   // 3.2M floats

    // workspace layout (~145.4 MB)
    float* u_cur  = (float*)d_ws;
    float* u_next = u_cur + U;
    float* i_cur  = u_next + U;
    float* i_next = i_cur + I;
    int* r_rowptr  = (int*)(i_next + I);                 // NUM_USERS+1
    int* rt_rowptr = r_rowptr + (NUM_USERS + 1);         // NUM_ITEMS+1
    int* s_rowptr  = rt_rowptr + (NUM_ITEMS + 1);        // NUM_USERS+1
    int* cursor    = s_rowptr + (NUM_USERS + 1);         // NUM_USERS+1 (reused per build)
    int*   r_colp  = cursor + (NUM_USERS + 1);
    float* r_valp  = (float*)(r_colp + NNZ_R);
    int*   rt_colp = (int*)(r_valp + NNZ_R);
    float* rt_valp = (float*)(rt_colp + NNZ_R);
    int*   s_colp  = (int*)(rt_valp + NNZ_R);
    float* s_valp  = (float*)(s_colp + NNZ_S);

    float* acc_u = (float*)d_out;        // final_user accumulator, normalized in place
    float* acc_i = (float*)d_out + U;    // final_item accumulator

    dim3 blk(256);

    init_kernel<<<2048, blk, 0, stream>>>(user_emb, item_emb, u_cur, i_cur, acc_u, acc_i,
                                          (int)(U / 4), (int)(I / 4));

    // ---- build 3 CSRs ----
    // R (group by user row)
    hipMemsetAsync(cursor, 0, (NUM_USERS + 1) * sizeof(int), stream);
    hist_kernel<<<2048, blk, 0, stream>>>(r_rows, cursor, NNZ_R);
    exscan_kernel<<<1, 1024, 0, stream>>>(cursor, r_rowptr, NUM_USERS);
    scatter_kernel<<<2048, blk, 0, stream>>>(r_rows, r_cols, r_vals, cursor, r_colp, r_valp, NNZ_R);
    // R^T (group by item)
    hipMemsetAsync(cursor, 0, (NUM_ITEMS + 1) * sizeof(int), stream);
    hist_kernel<<<2048, blk, 0, stream>>>(r_cols, cursor, NNZ_R);
    exscan_kernel<<<1, 1024, 0, stream>>>(cursor, rt_rowptr, NUM_ITEMS);
    scatter_kernel<<<2048, blk, 0, stream>>>(r_cols, r_rows, r_vals, cursor, rt_colp, rt_valp, NNZ_R);
    // S (group by user row)
    hipMemsetAsync(cursor, 0, (NUM_USERS + 1) * sizeof(int), stream);
    hist_kernel<<<2048, blk, 0, stream>>>(s_rows, cursor, NNZ_S);
    exscan_kernel<<<1, 1024, 0, stream>>>(cursor, s_rowptr, NUM_USERS);
    scatter_kernel<<<2048, blk, 0, stream>>>(s_rows, s_cols, s_vals, cursor, s_colp, s_valp, NNZ_S);

    // ---- 3 bipartite LightGCN layers (simultaneous update from old u,i) ----
    const float WU = 0.6f / 4.0f;    // 0.15
    const float WI = 0.25f;
    const float WS = 0.4f / 3.0f;
    int ublocks = (NUM_USERS + 3) / 4;
    int iblocks = (NUM_ITEMS + 3) / 4;
    for (int layer = 0; layer < 3; ++layer) {
        spmm_csr<<<ublocks, blk, 0, stream>>>(r_rowptr, r_colp, r_valp, i_cur, u_next, acc_u, WU, NUM_USERS);
        spmm_csr<<<iblocks, blk, 0, stream>>>(rt_rowptr, rt_colp, rt_valp, u_cur, i_next, acc_i, WI, NUM_ITEMS);
        std::swap(u_cur, u_next);
        std::swap(i_cur, i_next);
    }

    // ---- 2 social layers (restart from user_emb) ----
    hipMemcpyAsync(u_cur, user_emb, U * sizeof(float), hipMemcpyDeviceToDevice, stream);
    for (int layer = 0; layer < 2; ++layer) {
        spmm_csr<<<ublocks, blk, 0, stream>>>(s_rowptr, s_colp, s_valp, u_cur, u_next, acc_u, WS, NUM_USERS);
        std::swap(u_cur, u_next);
    }

    // ---- L2 normalize everything in place ----
    finalize_kernel<<<(NUM_USERS + NUM_ITEMS + 3) / 4, blk, 0, stream>>>((float*)d_out,
                                                                         NUM_USERS + NUM_ITEMS);
}

// Round 3
// 2030.109 us; speedup vs baseline: 2.5438x; 1.2052x over previous
//
#include <hip/hip_runtime.h>

constexpr int NUM_USERS = 100000;
constexpr int NUM_ITEMS = 50000;
constexpr int DIM = 64;
constexpr int NNZ_R = 3200000;
constexpr int NNZ_S = 2000000;

// ---- fused histograms (counts land at P+1 so the same array becomes rowptr) ----
__global__ void hist_r(const int* __restrict__ rows, const int* __restrict__ cols,
                       int* __restrict__ cntU, int* __restrict__ cntI, int nnz) {
    int i = blockIdx.x * blockDim.x + threadIdx.x;
    int st = gridDim.x * blockDim.x;
    for (; i < nnz; i += st) {
        atomicAdd(&cntU[rows[i]], 1);
        atomicAdd(&cntI[cols[i]], 1);
    }
}

__global__ void hist_s(const int* __restrict__ rows, int* __restrict__ cnt, int nnz) {
    int i = blockIdx.x * blockDim.x + threadIdx.x;
    int st = gridDim.x * blockDim.x;
    for (; i < nnz; i += st) atomicAdd(&cnt[rows[i]], 1);
}

// ---- 3 independent single-block exclusive scans in one dispatch ----
// Scans n counts at P[1..n] in place into exclusive starts; sets P[0]=0.
struct ScanArr { int* P; int n; };

__global__ __launch_bounds__(1024) void exscan3(ScanArr a0, ScanArr a1, ScanArr a2) {
    ScanArr A = (blockIdx.x == 0) ? a0 : (blockIdx.x == 1) ? a1 : a2;
    int* buf = A.P + 1;
    int n = A.n;
    __shared__ int part[1024];
    int t = threadIdx.x;
    int chunk = (n + 1023) >> 10;
    int lo = t * chunk, hi = min(lo + chunk, n);
    int s = 0;
    for (int i = lo; i < hi; ++i) s += buf[i];
    part[t] = s;
    __syncthreads();
    for (int off = 1; off < 1024; off <<= 1) {
        int v = (t >= off) ? part[t - off] : 0;
        __syncthreads();
        part[t] += v;
        __syncthreads();
    }
    int excl = (t == 0) ? 0 : part[t - 1];
    for (int i = lo; i < hi; ++i) {
        int c = buf[i];
        buf[i] = excl;   // exclusive start (cursor)
        excl += c;
    }
    if (t == 0) A.P[0] = 0;
}

// ---- fused scatter: one edge-list read emits both R and R^T packed CSRs ----
__global__ void scatter_r(const int* __restrict__ rows, const int* __restrict__ cols,
                          const float* __restrict__ vals, int* __restrict__ curU,
                          int* __restrict__ curI, int2* __restrict__ entU,
                          int2* __restrict__ entI, int nnz) {
    int i = blockIdx.x * blockDim.x + threadIdx.x;
    int st = gridDim.x * blockDim.x;
    for (; i < nnz; i += st) {
        int r = rows[i], c = cols[i];
        int v = __float_as_int(vals[i]);
        int pu = atomicAdd(&curU[r], 1);
        int pi = atomicAdd(&curI[c], 1);
        entU[pu] = make_int2(c, v);
        entI[pi] = make_int2(r, v);
    }
}

__global__ void scatter_s(const int* __restrict__ rows, const int* __restrict__ cols,
                          const float* __restrict__ vals, int* __restrict__ cur,
                          int2* __restrict__ ent, int nnz) {
    int i = blockIdx.x * blockDim.x + threadIdx.x;
    int st = gridDim.x * blockDim.x;
    for (; i < nnz; i += st) {
        int pos = atomicAdd(&cur[rows[i]], 1);
        ent[pos] = make_int2(cols[i], __float_as_int(vals[i]));
    }
}

// ---- CSR SpMM: one row per wave, 8 gathers in flight, fused weighted acc ----
struct SpmmOp {
    const int* P;      // n+1: P[r]=start, P[r+1]=end (post-scatter cursor values)
    const int2* ent;   // packed (col, val_bits)
    const float* x;
    float* out;        // may be nullptr (acc-only)
    float* acc;
    float w;
    int nrows;
};

__global__ void spmm2(SpmmOp A, SpmmOp B, int ablocks) {
    bool isA = (int)blockIdx.x < ablocks;
    SpmmOp op = isA ? A : B;
    int bid = isA ? blockIdx.x : blockIdx.x - ablocks;
    int row = bid * 4 + (threadIdx.x >> 6);
    if (row >= op.nrows) return;
    int d = threadIdx.x & 63;
    const int2* __restrict__ ent = op.ent;
    const float* __restrict__ x = op.x;
    int e = op.P[row], end = op.P[row + 1];
    float s0 = 0.f, s1 = 0.f, s2 = 0.f, s3 = 0.f, s4 = 0.f, s5 = 0.f, s6 = 0.f, s7 = 0.f;
    for (; e + 8 <= end; e += 8) {
        int2 e0 = ent[e],     e1 = ent[e + 1], e2 = ent[e + 2], e3 = ent[e + 3];
        int2 e4 = ent[e + 4], e5 = ent[e + 5], e6 = ent[e + 6], e7 = ent[e + 7];
        s0 += __int_as_float(e0.y) * x[(size_t)e0.x * DIM + d];
        s1 += __int_as_float(e1.y) * x[(size_t)e1.x * DIM + d];
        s2 += __int_as_float(e2.y) * x[(size_t)e2.x * DIM + d];
        s3 += __int_as_float(e3.y) * x[(size_t)e3.x * DIM + d];
        s4 += __int_as_float(e4.y) * x[(size_t)e4.x * DIM + d];
        s5 += __int_as_float(e5.y) * x[(size_t)e5.x * DIM + d];
        s6 += __int_as_float(e6.y) * x[(size_t)e6.x * DIM + d];
        s7 += __int_as_float(e7.y) * x[(size_t)e7.x * DIM + d];
    }
    for (; e < end; ++e) {
        int2 t = ent[e];
        s0 += __int_as_float(t.y) * x[(size_t)t.x * DIM + d];
    }
    float sum = ((s0 + s1) + (s2 + s3)) + ((s4 + s5) + (s6 + s7));
    size_t idx = (size_t)row * DIM + d;
    if (op.out) op.out[idx] = sum;
    op.acc[idx] += op.w * sum;
}

// acc_u = (0.6/4 + 0.4/3)*user_emb ; acc_i = 0.25*item_emb
__global__ void init_acc(const float* __restrict__ ue, const float* __restrict__ ie,
                         float* __restrict__ accU, float* __restrict__ accI,
                         int u4, int i4) {
    const float wu = 0.6f / 4.0f + 0.4f / 3.0f;
    const float wi = 0.25f;
    int i = blockIdx.x * blockDim.x + threadIdx.x;
    int st = gridDim.x * blockDim.x;
    int n4 = u4 + i4;
    for (; i < n4; i += st) {
        if (i < u4) {
            float4 v = reinterpret_cast<const float4*>(ue)[i];
            reinterpret_cast<float4*>(accU)[i] = make_float4(wu * v.x, wu * v.y, wu * v.z, wu * v.w);
        } else {
            int j = i - u4;
            float4 v = reinterpret_cast<const float4*>(ie)[j];
            reinterpret_cast<float4*>(accI)[j] = make_float4(wi * v.x, wi * v.y, wi * v.z, wi * v.w);
        }
    }
}

__global__ void finalize_kernel(float* __restrict__ out, int nrows) {
    int row = blockIdx.x * 4 + (threadIdx.x >> 6);
    if (row >= nrows) return;
    int d = threadIdx.x & 63;
    int idx = row * DIM + d;
    float val = out[idx];
    float sq = val * val;
    #pragma unroll
    for (int off = 32; off; off >>= 1) sq += __shfl_xor(sq, off, 64);
    out[idx] = val / fmaxf(sqrtf(sq), 1e-12f);
}

extern "C" void kernel_launch(void* const* d_in, const int* in_sizes, int n_in,
                              void* d_out, int out_size, void* d_ws, size_t ws_size,
                              hipStream_t stream) {
    const float* user_emb = (const float*)d_in[0];
    const float* item_emb = (const float*)d_in[1];
    const float* r_vals   = (const float*)d_in[2];
    const float* s_vals   = (const float*)d_in[3];
    const int*   r_rows   = (const int*)d_in[4];
    const int*   r_cols   = (const int*)d_in[5];
    const int*   s_rows   = (const int*)d_in[6];
    const int*   s_cols   = (const int*)d_in[7];

    const size_t U = (size_t)NUM_USERS * DIM;
    const size_t I = (size_t)NUM_ITEMS * DIM;

    // workspace layout (145.0 MB)
    int2* r_ent  = (int2*)d_ws;          // NNZ_R
    int2* rt_ent = r_ent + NNZ_R;        // NNZ_R
    int2* s_ent  = rt_ent + NNZ_R;       // NNZ_S
    float* uA = (float*)(s_ent + NNZ_S); // U
    float* uB = uA + U;                  // U
    float* iA = uB + U;                  // I
    float* iB = iA + I;                  // I
    int* rP  = (int*)(iB + I);           // NUM_USERS+1   (counts -> cursor -> rowptr)
    int* rtP = rP + (NUM_USERS + 1);     // NUM_ITEMS+1
    int* sP  = rtP + (NUM_ITEMS + 1);    // NUM_USERS+1

    float* accU = (float*)d_out;
    float* accI = (float*)d_out + U;

    dim3 blk(256);
    const int PTOT = (NUM_USERS + 1) + (NUM_ITEMS + 1) + (NUM_USERS + 1);

    hipMemsetAsync(rP, 0, PTOT * sizeof(int), stream);
    init_acc<<<2048, blk, 0, stream>>>(user_emb, item_emb, accU, accI,
                                       (int)(U / 4), (int)(I / 4));

    // ---- build all 3 CSRs in 5 dispatches ----
    hist_r<<<2048, blk, 0, stream>>>(r_rows, r_cols, rP + 1, rtP + 1, NNZ_R);
    hist_s<<<2048, blk, 0, stream>>>(s_rows, sP + 1, NNZ_S);
    ScanArr sa0{rP, NUM_USERS}, sa1{rtP, NUM_ITEMS}, sa2{sP, NUM_USERS};
    exscan3<<<3, 1024, 0, stream>>>(sa0, sa1, sa2);
    scatter_r<<<2048, blk, 0, stream>>>(r_rows, r_cols, r_vals, rP + 1, rtP + 1,
                                        r_ent, rt_ent, NNZ_R);
    scatter_s<<<2048, blk, 0, stream>>>(s_rows, s_cols, s_vals, sP + 1, s_ent, NNZ_S);

    // ---- propagation: both bipartite directions fused per layer ----
    const float WU = 0.6f / 4.0f, WI = 0.25f, WS = 0.4f / 3.0f;
    int ub = (NUM_USERS + 3) / 4, ib = (NUM_ITEMS + 3) / 4;

    SpmmOp u1{rP, r_ent, item_emb, uA, accU, WU, NUM_USERS};
    SpmmOp i1{rtP, rt_ent, user_emb, iA, accI, WI, NUM_ITEMS};
    spmm2<<<ub + ib, blk, 0, stream>>>(u1, i1, ub);

    SpmmOp u2{rP, r_ent, iA, uB, accU, WU, NUM_USERS};
    SpmmOp i2{rtP, rt_ent, uA, iB, accI, WI, NUM_ITEMS};
    spmm2<<<ub + ib, blk, 0, stream>>>(u2, i2, ub);

    SpmmOp u3{rP, r_ent, iB, nullptr, accU, WU, NUM_USERS};
    SpmmOp i3{rtP, rt_ent, uB, nullptr, accI, WI, NUM_ITEMS};
    spmm2<<<ub + ib, blk, 0, stream>>>(u3, i3, ub);

    // ---- social layers (uA is dead after layer 2 -> reuse) ----
    SpmmOp so1{sP, s_ent, user_emb, uA, accU, WS, NUM_USERS};
    spmm2<<<ub, blk, 0, stream>>>(so1, so1, ub);
    SpmmOp so2{sP, s_ent, uA, nullptr, accU, WS, NUM_USERS};
    spmm2<<<ub, blk, 0, stream>>>(so2, so2, ub);

    finalize_kernel<<<(NUM_USERS + NUM_ITEMS + 3) / 4, blk, 0, stream>>>(
        (float*)d_out, NUM_USERS + NUM_ITEMS);
}